// Round 10
// baseline (234.158 us; speedup 1.0000x reference)
//
#include <hip/hip_runtime.h>
#include <math.h>

#define DIM   1024
#define HEADS 16
#define HDIM  64
#define SEQ   1024
#define BATCH 8
// SCALE * log2(e): Q is pre-scaled by this in the QKV epilogue so attention
// can use exp2 directly: exp2(s*SCALE*log2e) == exp(s*SCALE).
#define QSCALE 0.1803368801111204f
#define LDH   72       // P/Q LDS row stride in bf16 (64 + 8 pad)
#define ABM   128      // attention query tile (2 Q-fragments per wave)

typedef __attribute__((ext_vector_type(8)))  short          short8_t;   // MFMA bf16 frag
typedef __attribute__((ext_vector_type(8)))  unsigned short ushort8_t;
typedef __attribute__((ext_vector_type(4)))  unsigned short ushort4_t;
typedef __attribute__((ext_vector_type(4)))  float          floatx4;
typedef __attribute__((ext_vector_type(16))) float          floatx16;

__device__ __forceinline__ unsigned short f2bf(float f) {
    unsigned u = __float_as_uint(f);
    u += 0x7fffu + ((u >> 16) & 1u);      // round-to-nearest-even
    return (unsigned short)(u >> 16);
}
__device__ __forceinline__ unsigned rnd_bf(float f) {  // RNE-rounded, bf16 in bits 31:16
    unsigned u = __float_as_uint(f);
    return u + 0x7fffu + ((u >> 16) & 1u);
}
__device__ __forceinline__ float fast_exp2(float x) {
#if __has_builtin(__builtin_amdgcn_exp2f)
    return __builtin_amdgcn_exp2f(x);
#else
    return exp2f(x);
#endif
}
__device__ __forceinline__ void glds16(const unsigned short* g, unsigned short* l) {
    __builtin_amdgcn_global_load_lds(
        (const __attribute__((address_space(1))) void*)g,
        (__attribute__((address_space(3))) void*)l, 16, 0, 0);
}

// ---------------------------------------------------------------------------
// Fused fp32 -> bf16 cast of x, W_qkv, W_proj in one launch (8 elems/thread).
// ---------------------------------------------------------------------------
__global__ __launch_bounds__(256) void cvt_bf16_all(const float* __restrict__ x,
                                                    const float* __restrict__ wqkv,
                                                    const float* __restrict__ wproj,
                                                    unsigned short* __restrict__ x_o,
                                                    unsigned short* __restrict__ wqkv_o,
                                                    unsigned short* __restrict__ wproj_o) {
    const int N8_X = BATCH * SEQ * DIM / 8;         // 1048576
    const int N8_WQ = 3 * DIM * DIM / 8;            // 393216
    const int N8_WP = DIM * DIM / 8;                // 131072
    int i = blockIdx.x * 256 + threadIdx.x;
    const float* in;
    unsigned short* out;
    if (i < N8_X)               { in = x;     out = x_o; }
    else if (i < N8_X + N8_WQ)  { i -= N8_X;  in = wqkv; out = wqkv_o; }
    else                        { i -= N8_X + N8_WQ;
                                  if (i >= N8_WP) return;
                                  in = wproj; out = wproj_o; }
    const float4* p = (const float4*)in + (size_t)i * 2;
    float4 a = p[0], b = p[1];
    ushort8_t u;
    u[0] = f2bf(a.x); u[1] = f2bf(a.y); u[2] = f2bf(a.z); u[3] = f2bf(a.w);
    u[4] = f2bf(b.x); u[5] = f2bf(b.y); u[6] = f2bf(b.z); u[7] = f2bf(b.w);
    ((ushort8_t*)out)[i] = u;
}

// ---------------------------------------------------------------------------
// C[M,N] = A[M,K] @ B[N,K]^T, bf16 in, fp32 MFMA accumulate.
// r8 structure (BK=64, 2-barrier glds, 8-chunk xor swizzle — measured 0 LDS
// conflicts) but with 32x32x16 MFMA: wave tile 64x64 = 2x2 accs of 32x32.
// 16 MFMAs/wave/iter (vs 32 at 16x16) at the higher 32x32 µbench rate
// (2382 vs 2075 TF) and half the ds_read->MFMA dependency chain length.
// A/B frag: [m=lane&31][k=(lane>>5)*8+j]; C/D: col=lane&31,
// row=(reg&3)+8*(reg>>2)+4*(lane>>5)  [measured m74/m101].
// GRID IS (M-tiles, N-tiles): x fastest -> A-tile sharers stay on one XCD.
// MODE 0: fp32 out + bias. MODE 2: QKV split — cols<1024 -> Q bf16 *QSCALE;
// 1024..2047 -> K bf16; >=2048 -> V TRANSPOSED to vt[b][h][d][token].
// ---------------------------------------------------------------------------
template<int MODE>
__global__ __launch_bounds__(256) void gemm_nt_mfma(const unsigned short* __restrict__ A,
                                                    const unsigned short* __restrict__ B,
                                                    const float* __restrict__ bias,
                                                    void* __restrict__ Cout,
                                                    unsigned short* __restrict__ vt,
                                                    int M, int N, int K) {
    __shared__ __align__(16) unsigned short As[128 * 64];   // 16 KB
    __shared__ __align__(16) unsigned short Bs[128 * 64];   // 16 KB

    const int tid  = threadIdx.x;
    const int lane = tid & 63;
    const int wave = tid >> 6;
    const int wm = (wave >> 1) * 64;
    const int wn = (wave & 1) * 64;
    const size_t brow = (size_t)blockIdx.x * 128;   // M fastest (XCD locality)
    const size_t bcol = (size_t)blockIdx.y * 128;

    // staging (r8, verified conflict-free): round r covers rows [r*32,+32);
    // wave w takes rows w*8..w*8+7, lane l -> row off l>>3, swizzled chunk.
    const int srow   = lane >> 3;                 // 0..7
    const int schunk = (lane & 7) ^ srow;         // xor-swizzled global chunk
    const unsigned short* gA = A + (brow + wave * 8 + srow) * (size_t)K + schunk * 8;
    const unsigned short* gB = B + (bcol + wave * 8 + srow) * (size_t)K + schunk * 8;
    unsigned short* lA = &As[wave * 512 + lane * 8];
    unsigned short* lB = &Bs[wave * 512 + lane * 8];

    floatx16 acc[2][2];
    #pragma unroll
    for (int i = 0; i < 2; i++)
        #pragma unroll
        for (int j = 0; j < 2; j++)
            #pragma unroll
            for (int r = 0; r < 16; r++) acc[i][j][r] = 0.f;

    const int c32  = lane & 31;   // frag row (m for A, n for B)
    const int half = lane >> 5;   // k-half selector
    const int xr   = c32 & 7;     // row xor for swizzled reads

    for (int k0 = 0; k0 < K; k0 += 64) {
        __syncthreads();
        #pragma unroll
        for (int r = 0; r < 4; r++) {
            glds16(gA + (size_t)r * 32 * K + k0, lA + r * 2048);
            glds16(gB + (size_t)r * 32 * K + k0, lB + r * 2048);
        }
        __syncthreads();

        #pragma unroll
        for (int s = 0; s < 4; s++) {   // 4 k-steps of 16
            const int ch = ((s * 2 + half) ^ xr) * 8;   // swizzled chunk offset
            short8_t a0 = *(const short8_t*)&As[(wm + c32) * 64 + ch];
            short8_t a1 = *(const short8_t*)&As[(wm + 32 + c32) * 64 + ch];
            short8_t b0 = *(const short8_t*)&Bs[(wn + c32) * 64 + ch];
            short8_t b1 = *(const short8_t*)&Bs[(wn + 32 + c32) * 64 + ch];
            acc[0][0] = __builtin_amdgcn_mfma_f32_32x32x16_bf16(a0, b0, acc[0][0], 0, 0, 0);
            acc[0][1] = __builtin_amdgcn_mfma_f32_32x32x16_bf16(a0, b1, acc[0][1], 0, 0, 0);
            acc[1][0] = __builtin_amdgcn_mfma_f32_32x32x16_bf16(a1, b0, acc[1][0], 0, 0, 0);
            acc[1][1] = __builtin_amdgcn_mfma_f32_32x32x16_bf16(a1, b1, acc[1][1], 0, 0, 0);
        }
    }

    // C/D: col = c32, row = (r&3) + 8*(r>>2) + 4*half
    if (MODE == 0) {
        #pragma unroll
        for (int mi = 0; mi < 2; mi++)
            #pragma unroll
            for (int ni = 0; ni < 2; ni++) {
                const size_t col = bcol + wn + ni * 32 + c32;
                const float bv = bias[col];
                #pragma unroll
                for (int r = 0; r < 16; r++) {
                    const size_t row = brow + wm + mi * 32 + (r & 3) + 8 * (r >> 2) + 4 * half;
                    ((float*)Cout)[row * N + col] = acc[mi][ni][r] + bv;
                }
            }
    } else {  // MODE 2
        if (bcol < 2048) {
            const float sc = (bcol < 1024) ? QSCALE : 1.0f;  // pre-scale Q
            unsigned short* qk = (unsigned short*)Cout;
            #pragma unroll
            for (int mi = 0; mi < 2; mi++)
                #pragma unroll
                for (int ni = 0; ni < 2; ni++) {
                    const size_t col = bcol + wn + ni * 32 + c32;
                    #pragma unroll
                    for (int r = 0; r < 16; r++) {
                        const size_t row = brow + wm + mi * 32 + (r & 3) + 8 * (r >> 2) + 4 * half;
                        qk[row * 2048 + col] = f2bf(acc[mi][ni][r] * sc);
                    }
                }
        } else {
            #pragma unroll
            for (int mi = 0; mi < 2; mi++)
                #pragma unroll
                for (int ni = 0; ni < 2; ni++) {
                    const int dall = (int)(bcol + wn + ni * 32 + c32) - 2048;
                    const int h = dall >> 6, d = dall & 63;
                    #pragma unroll
                    for (int rg = 0; rg < 4; rg++) {   // reg-quad = 4 consecutive rows
                        const size_t row0 = brow + wm + mi * 32 + rg * 8 + 4 * half;
                        const size_t bb = row0 >> 10;
                        const int n0 = (int)(row0 & 1023);
                        ushort4_t o;
                        #pragma unroll
                        for (int q = 0; q < 4; q++) o[q] = f2bf(acc[mi][ni][rg * 4 + q]);
                        *(ushort4_t*)&vt[(((size_t)bb * HEADS + h) * HDIM + d) * SEQ + n0] = o;
                    }
                }
        }
    }
}

// ---------------------------------------------------------------------------
// MFMA flash attention, S^T formulation, ABM=128, double-buffered K/V LDS,
// one barrier per key-tile; prefetch loads issued AFTER the barrier (r9).
// K/V buffers xor-swizzled (stride 64, conflict-free, r7).
// Grid = (b*HEADS+h, qt): q-tiles of one (b,h) share an XCD.
// ---------------------------------------------------------------------------
__global__ __launch_bounds__(256) void attn_mfma(const unsigned short* __restrict__ qk,
                                                 const unsigned short* __restrict__ vt,
                                                 unsigned short* __restrict__ aout) {
    const int bh = blockIdx.x;           // b*HEADS + h
    const int qt = blockIdx.y;           // 0..7
    const int h  = bh & 15;
    const int b  = bh >> 4;
    const int tid  = threadIdx.x;
    const int lane = tid & 63;
    const int wave = tid >> 6;
    const int g = lane >> 4;     // quad group
    const int c = lane & 15;     // query for S^T; dim-col for PV output

    __shared__ __align__(16) unsigned short Qs[ABM * LDH];      // Q then P
    __shared__ __align__(16) unsigned short Ks[2][64 * 64];     // swizzled
    __shared__ __align__(16) unsigned short Vs[2][64 * 64];     // V^T, swizzled
    __shared__ float scr[4][2][16];

    const int sr = tid >> 2;   // K/V staging row 0..63
    const int sq = tid & 3;    // two 16B chunks: 2sq, 2sq+1 (pre-swizzle)
    const int sx = sr & 7;     // staging row xor
    const unsigned short* ksrc0 =
        qk + ((size_t)(b * SEQ + sr)) * 2048 + DIM + h * HDIM + sq * 16;
    const unsigned short* vsrc0 =
        vt + (((size_t)(b * HEADS + h)) * HDIM + sr) * SEQ + sq * 16;
    // swizzled LDS staging offsets (bf16 units): row*64 + (chunk^xr)*8
    const int kvo0 = sr * 64 + (((sq * 2)     ^ sx) * 8);
    const int kvo1 = sr * 64 + (((sq * 2 + 1) ^ sx) * 8);

    // prefetch K/V tile 0 into registers
    ushort8_t ck0 = *(const ushort8_t*)ksrc0;
    ushort8_t ck1 = *(const ushort8_t*)(ksrc0 + 8);
    ushort8_t cv0 = *(const ushort8_t*)vsrc0;
    ushort8_t cv1 = *(const ushort8_t*)(vsrc0 + 8);

    // stage Q tile: 128 rows x 64 cols; thread -> row tid>>1, 32-col half
    {
        const int r  = tid >> 1;
        const int c0 = (tid & 1) * 32;
        const unsigned short* src =
            qk + ((size_t)(b * SEQ + qt * ABM + r)) * 2048 + h * HDIM + c0;
        unsigned short* dst = &Qs[r * LDH + c0];
        *(ushort8_t*)(dst)      = *(const ushort8_t*)(src);
        *(ushort8_t*)(dst + 8)  = *(const ushort8_t*)(src + 8);
        *(ushort8_t*)(dst + 16) = *(const ushort8_t*)(src + 16);
        *(ushort8_t*)(dst + 24) = *(const ushort8_t*)(src + 24);
    }
    __syncthreads();

    // Q B-fragments, register-resident for the whole kernel
    short8_t bq[2][2];
    #pragma unroll
    for (int f = 0; f < 2; f++)
        #pragma unroll
        for (int kc = 0; kc < 2; kc++)
            bq[f][kc] = *(const short8_t*)&Qs[(f * 64 + wave * 16 + c) * LDH + g * 8 + kc * 32];

    floatx4 O[2][4];
    #pragma unroll
    for (int f = 0; f < 2; f++)
        #pragma unroll
        for (int i = 0; i < 4; i++) O[f][i] = (floatx4){0.f, 0.f, 0.f, 0.f};
    float lsum[2] = {0.f, 0.f};

    // frag-read swizzled chunk offsets (row&7 == c&7 since rows step by 16)
    const int fro0 = ((0 * 4 + g) ^ (c & 7)) * 8;   // kc=0
    const int fro1 = ((1 * 4 + g) ^ (c & 7)) * 8;   // kc=1

    for (int kt = 0; kt < SEQ / 64; kt++) {
        const int cur = kt & 1;
        // write prefetched K/V into buf[cur] (vmcnt wait lands here, a full
        // MFMA phase after the loads were issued)
        *(ushort8_t*)&Ks[cur][kvo0] = ck0;
        *(ushort8_t*)&Ks[cur][kvo1] = ck1;
        *(ushort8_t*)&Vs[cur][kvo0] = cv0;
        *(ushort8_t*)&Vs[cur][kvo1] = cv1;
        __syncthreads();   // ONE barrier per tile; vmcnt already drained
        // issue next tile's global loads AFTER the barrier
        if (kt + 1 < SEQ / 64) {
            const unsigned short* ks = ksrc0 + (size_t)(kt + 1) * 64 * 2048;
            const unsigned short* vs = vsrc0 + (kt + 1) * 64;
            ck0 = *(const ushort8_t*)ks;
            ck1 = *(const ushort8_t*)(ks + 8);
            cv0 = *(const ushort8_t*)vs;
            cv1 = *(const ushort8_t*)(vs + 8);
        }

        // K fragments (shared across both Q-frags)
        short8_t ak[4][2];
        #pragma unroll
        for (int nt = 0; nt < 4; nt++) {
            ak[nt][0] = *(const short8_t*)&Ks[cur][(nt * 16 + c) * 64 + fro0];
            ak[nt][1] = *(const short8_t*)&Ks[cur][(nt * 16 + c) * 64 + fro1];
        }

        // S^T = K Q^T : rows = keys nt*16+g*4+r, col = query c (per f)
        floatx4 S[2][4];
        #pragma unroll
        for (int f = 0; f < 2; f++)
            #pragma unroll
            for (int nt = 0; nt < 4; nt++) S[f][nt] = (floatx4){0.f, 0.f, 0.f, 0.f};
        #pragma unroll
        for (int f = 0; f < 2; f++)
            #pragma unroll
            for (int nt = 0; nt < 4; nt++)
                #pragma unroll
                for (int kc = 0; kc < 2; kc++)
                    S[f][nt] = __builtin_amdgcn_mfma_f32_16x16x32_bf16(
                        ak[nt][kc], bq[f][kc], S[f][nt], 0, 0, 0);

        // p = exp2(s); accumulate l in-lane; pack 4 keys -> 8B write
        #pragma unroll
        for (int f = 0; f < 2; f++)
            #pragma unroll
            for (int nt = 0; nt < 4; nt++) {
                const float p0 = fast_exp2(S[f][nt][0]);
                const float p1 = fast_exp2(S[f][nt][1]);
                const float p2 = fast_exp2(S[f][nt][2]);
                const float p3 = fast_exp2(S[f][nt][3]);
                lsum[f] += (p0 + p1) + (p2 + p3);
                const unsigned r01 = __builtin_amdgcn_perm(rnd_bf(p1), rnd_bf(p0), 0x07060302);
                const unsigned r23 = __builtin_amdgcn_perm(rnd_bf(p3), rnd_bf(p2), 0x07060302);
                *(uint2*)&Qs[(f * 64 + wave * 16 + c) * LDH + nt * 16 + g * 4] =
                    make_uint2(r01, r23);
            }

        // V^T fragments (shared across both Q-frags)
        short8_t bv[4][2];
        #pragma unroll
        for (int dnt = 0; dnt < 4; dnt++) {
            bv[dnt][0] = *(const short8_t*)&Vs[cur][(dnt * 16 + c) * 64 + fro0];
            bv[dnt][1] = *(const short8_t*)&Vs[cur][(dnt * 16 + c) * 64 + fro1];
        }

        // PV: O[query][dim] += P[query][key] V^T[dim][key]
        #pragma unroll
        for (int f = 0; f < 2; f++) {
            short8_t ap[2];
            #pragma unroll
            for (int kc = 0; kc < 2; kc++)
                ap[kc] = *(const short8_t*)&Qs[(f * 64 + wave * 16 + c) * LDH + g * 8 + kc * 32];
            #pragma unroll
            for (int dnt = 0; dnt < 4; dnt++)
                #pragma unroll
                for (int kc = 0; kc < 2; kc++)
                    O[f][dnt] = __builtin_amdgcn_mfma_f32_16x16x32_bf16(
                        ap[kc], bv[dnt][kc], O[f][dnt], 0, 0, 0);
        }
    }

    // epilogue: reduce l over the 4 g-lanes per query, broadcast 1/l via LDS
    #pragma unroll
    for (int f = 0; f < 2; f++) {
        float s = lsum[f];
        s += __shfl_xor(s, 16);
        s += __shfl_xor(s, 32);
        if (g == 0) scr[wave][f][c] = 1.0f / s;
    }
    __builtin_amdgcn_s_waitcnt(0);   // lgkm drain for same-wave LDS ordering

    #pragma unroll
    for (int f = 0; f < 2; f++) {
        const float4 inv4 = *(const float4*)&scr[wave][f][g * 4];
        #pragma unroll
        for (int r = 0; r < 4; r++) {
            const float invl = ((const float*)&inv4)[r];
            const size_t row = (size_t)b * SEQ + qt * ABM + f * 64 + wave * 16 + g * 4 + r;
            #pragma unroll
            for (int dnt = 0; dnt < 4; dnt++)
                aout[row * DIM + h * HDIM + dnt * 16 + c] = f2bf(O[f][dnt][r] * invl);
        }
    }
}

// ---------------------------------------------------------------------------
extern "C" void kernel_launch(void* const* d_in, const int* in_sizes, int n_in,
                              void* d_out, int out_size, void* d_ws, size_t ws_size,
                              hipStream_t stream) {
    const float* x      = (const float*)d_in[0];   // [8,1024,1024]
    const float* W_qkv  = (const float*)d_in[1];   // [3072,1024]
    const float* W_proj = (const float*)d_in[2];   // [1024,1024]
    const float* b_proj = (const float*)d_in[3];   // [1024]
    float* out = (float*)d_out;                    // [8,1024,1024] fp32

    const int M = BATCH * SEQ;                     // 8192

    // workspace (bf16 elements), ~92.3 MB total
    unsigned short* ws       = (unsigned short*)d_ws;
    unsigned short* x_bf     = ws;                                   // 8192*1024
    unsigned short* wqkv_bf  = x_bf + (size_t)M * DIM;               // 3072*1024
    unsigned short* wproj_bf = wqkv_bf + (size_t)3 * DIM * DIM;      // 1024*1024
    unsigned short* qk_bf    = wproj_bf + (size_t)DIM * DIM;         // 8192*2048
    unsigned short* vt_bf    = qk_bf + (size_t)M * 2048;             // 16*64*8*1024
    unsigned short* aout_bf  = vt_bf + (size_t)BATCH * HEADS * HDIM * SEQ;  // 8192*1024

    // 0) fused casts (x, W_qkv, W_proj)
    {
        const int n8 = (M * DIM + 3 * DIM * DIM + DIM * DIM) / 8;
        cvt_bf16_all<<<(n8 + 255) / 256, 256, 0, stream>>>(
            x, W_qkv, W_proj, x_bf, wqkv_bf, wproj_bf);
    }

    // 1) QKV projection: Q (pre-scaled) + K natural bf16, V -> vt[b][h][d][n]
    gemm_nt_mfma<2><<<dim3(M / 128, 3 * DIM / 128), 256, 0, stream>>>(
        x_bf, wqkv_bf, nullptr, qk_bf, vt_bf, M, 3 * DIM, DIM);

    // 2) MFMA flash attention; grid x = (b,h) so q-tiles share an XCD
    attn_mfma<<<dim3(BATCH * HEADS, SEQ / ABM), 256, 0, stream>>>(qk_bf, vt_bf, aout_bf);

    // 3) output projection (fp32 out + bias)
    gemm_nt_mfma<0><<<dim3(M / 128, DIM / 128), 256, 0, stream>>>(
        aout_bf, wproj_bf, b_proj, out, nullptr, M, DIM, DIM);
}

// Round 11
// 231.014 us; speedup vs baseline: 1.0136x; 1.0136x over previous
//
#include <hip/hip_runtime.h>
#include <math.h>

#define DIM   1024
#define HEADS 16
#define HDIM  64
#define SEQ   1024
#define BATCH 8
// SCALE * log2(e): Q is pre-scaled by this in the QKV epilogue so attention
// can use exp2 directly: exp2(s*SCALE*log2e) == exp(s*SCALE).
#define QSCALE 0.1803368801111204f
#define LDH   72       // P/Q LDS row stride in bf16 (64 + 8 pad)
#define ABM   128      // attention query tile (32 queries per wave)

typedef __attribute__((ext_vector_type(8)))  short          short8_t;   // MFMA bf16 frag
typedef __attribute__((ext_vector_type(8)))  unsigned short ushort8_t;
typedef __attribute__((ext_vector_type(4)))  unsigned short ushort4_t;
typedef __attribute__((ext_vector_type(4)))  float          floatx4;
typedef __attribute__((ext_vector_type(16))) float          floatx16;

__device__ __forceinline__ unsigned short f2bf(float f) {
    unsigned u = __float_as_uint(f);
    u += 0x7fffu + ((u >> 16) & 1u);      // round-to-nearest-even
    return (unsigned short)(u >> 16);
}
__device__ __forceinline__ unsigned rnd_bf(float f) {  // RNE-rounded, bf16 in bits 31:16
    unsigned u = __float_as_uint(f);
    return u + 0x7fffu + ((u >> 16) & 1u);
}
__device__ __forceinline__ float fast_exp2(float x) {
#if __has_builtin(__builtin_amdgcn_exp2f)
    return __builtin_amdgcn_exp2f(x);
#else
    return exp2f(x);
#endif
}
__device__ __forceinline__ void glds16(const unsigned short* g, unsigned short* l) {
    __builtin_amdgcn_global_load_lds(
        (const __attribute__((address_space(1))) void*)g,
        (__attribute__((address_space(3))) void*)l, 16, 0, 0);
}

// ---------------------------------------------------------------------------
// Fused fp32 -> bf16 cast of x, W_qkv, W_proj in one launch (8 elems/thread).
// ---------------------------------------------------------------------------
__global__ __launch_bounds__(256) void cvt_bf16_all(const float* __restrict__ x,
                                                    const float* __restrict__ wqkv,
                                                    const float* __restrict__ wproj,
                                                    unsigned short* __restrict__ x_o,
                                                    unsigned short* __restrict__ wqkv_o,
                                                    unsigned short* __restrict__ wproj_o) {
    const int N8_X = BATCH * SEQ * DIM / 8;         // 1048576
    const int N8_WQ = 3 * DIM * DIM / 8;            // 393216
    const int N8_WP = DIM * DIM / 8;                // 131072
    int i = blockIdx.x * 256 + threadIdx.x;
    const float* in;
    unsigned short* out;
    if (i < N8_X)               { in = x;     out = x_o; }
    else if (i < N8_X + N8_WQ)  { i -= N8_X;  in = wqkv; out = wqkv_o; }
    else                        { i -= N8_X + N8_WQ;
                                  if (i >= N8_WP) return;
                                  in = wproj; out = wproj_o; }
    const float4* p = (const float4*)in + (size_t)i * 2;
    float4 a = p[0], b = p[1];
    ushort8_t u;
    u[0] = f2bf(a.x); u[1] = f2bf(a.y); u[2] = f2bf(a.z); u[3] = f2bf(a.w);
    u[4] = f2bf(b.x); u[5] = f2bf(b.y); u[6] = f2bf(b.z); u[7] = f2bf(b.w);
    ((ushort8_t*)out)[i] = u;
}

// ---------------------------------------------------------------------------
// C[M,N] = A[M,K] @ B[N,K]^T, bf16 in, fp32 MFMA accumulate.  (unchanged r10)
// BK=64, 2-barrier glds, 8-chunk xor swizzle, 32x32x16 MFMA (2x2 accs/wave).
// A/B frag: [m=lane&31][k=(lane>>5)*8+j]; C/D: col=lane&31,
// row=(reg&3)+8*(reg>>2)+4*(lane>>5)  [measured m74/m101].
// GRID IS (M-tiles, N-tiles): x fastest -> A-tile sharers stay on one XCD.
// MODE 0: fp32 out + bias. MODE 2: QKV split — cols<1024 -> Q bf16 *QSCALE;
// 1024..2047 -> K bf16; >=2048 -> V TRANSPOSED to vt[b][h][d][token].
// ---------------------------------------------------------------------------
template<int MODE>
__global__ __launch_bounds__(256) void gemm_nt_mfma(const unsigned short* __restrict__ A,
                                                    const unsigned short* __restrict__ B,
                                                    const float* __restrict__ bias,
                                                    void* __restrict__ Cout,
                                                    unsigned short* __restrict__ vt,
                                                    int M, int N, int K) {
    __shared__ __align__(16) unsigned short As[128 * 64];   // 16 KB
    __shared__ __align__(16) unsigned short Bs[128 * 64];   // 16 KB

    const int tid  = threadIdx.x;
    const int lane = tid & 63;
    const int wave = tid >> 6;
    const int wm = (wave >> 1) * 64;
    const int wn = (wave & 1) * 64;
    const size_t brow = (size_t)blockIdx.x * 128;   // M fastest (XCD locality)
    const size_t bcol = (size_t)blockIdx.y * 128;

    const int srow   = lane >> 3;                 // 0..7
    const int schunk = (lane & 7) ^ srow;         // xor-swizzled global chunk
    const unsigned short* gA = A + (brow + wave * 8 + srow) * (size_t)K + schunk * 8;
    const unsigned short* gB = B + (bcol + wave * 8 + srow) * (size_t)K + schunk * 8;
    unsigned short* lA = &As[wave * 512 + lane * 8];
    unsigned short* lB = &Bs[wave * 512 + lane * 8];

    floatx16 acc[2][2];
    #pragma unroll
    for (int i = 0; i < 2; i++)
        #pragma unroll
        for (int j = 0; j < 2; j++)
            #pragma unroll
            for (int r = 0; r < 16; r++) acc[i][j][r] = 0.f;

    const int c32  = lane & 31;   // frag row (m for A, n for B)
    const int half = lane >> 5;   // k-half selector
    const int xr   = c32 & 7;     // row xor for swizzled reads

    for (int k0 = 0; k0 < K; k0 += 64) {
        __syncthreads();
        #pragma unroll
        for (int r = 0; r < 4; r++) {
            glds16(gA + (size_t)r * 32 * K + k0, lA + r * 2048);
            glds16(gB + (size_t)r * 32 * K + k0, lB + r * 2048);
        }
        __syncthreads();

        #pragma unroll
        for (int s = 0; s < 4; s++) {   // 4 k-steps of 16
            const int ch = ((s * 2 + half) ^ xr) * 8;   // swizzled chunk offset
            short8_t a0 = *(const short8_t*)&As[(wm + c32) * 64 + ch];
            short8_t a1 = *(const short8_t*)&As[(wm + 32 + c32) * 64 + ch];
            short8_t b0 = *(const short8_t*)&Bs[(wn + c32) * 64 + ch];
            short8_t b1 = *(const short8_t*)&Bs[(wn + 32 + c32) * 64 + ch];
            acc[0][0] = __builtin_amdgcn_mfma_f32_32x32x16_bf16(a0, b0, acc[0][0], 0, 0, 0);
            acc[0][1] = __builtin_amdgcn_mfma_f32_32x32x16_bf16(a0, b1, acc[0][1], 0, 0, 0);
            acc[1][0] = __builtin_amdgcn_mfma_f32_32x32x16_bf16(a1, b0, acc[1][0], 0, 0, 0);
            acc[1][1] = __builtin_amdgcn_mfma_f32_32x32x16_bf16(a1, b1, acc[1][1], 0, 0, 0);
        }
    }

    // C/D: col = c32, row = (r&3) + 8*(r>>2) + 4*half
    if (MODE == 0) {
        #pragma unroll
        for (int mi = 0; mi < 2; mi++)
            #pragma unroll
            for (int ni = 0; ni < 2; ni++) {
                const size_t col = bcol + wn + ni * 32 + c32;
                const float bv = bias[col];
                #pragma unroll
                for (int r = 0; r < 16; r++) {
                    const size_t row = brow + wm + mi * 32 + (r & 3) + 8 * (r >> 2) + 4 * half;
                    ((float*)Cout)[row * N + col] = acc[mi][ni][r] + bv;
                }
            }
    } else {  // MODE 2
        if (bcol < 2048) {
            const float sc = (bcol < 1024) ? QSCALE : 1.0f;  // pre-scale Q
            unsigned short* qk = (unsigned short*)Cout;
            #pragma unroll
            for (int mi = 0; mi < 2; mi++)
                #pragma unroll
                for (int ni = 0; ni < 2; ni++) {
                    const size_t col = bcol + wn + ni * 32 + c32;
                    #pragma unroll
                    for (int r = 0; r < 16; r++) {
                        const size_t row = brow + wm + mi * 32 + (r & 3) + 8 * (r >> 2) + 4 * half;
                        qk[row * 2048 + col] = f2bf(acc[mi][ni][r] * sc);
                    }
                }
        } else {
            #pragma unroll
            for (int mi = 0; mi < 2; mi++)
                #pragma unroll
                for (int ni = 0; ni < 2; ni++) {
                    const int dall = (int)(bcol + wn + ni * 32 + c32) - 2048;
                    const int h = dall >> 6, d = dall & 63;
                    #pragma unroll
                    for (int rg = 0; rg < 4; rg++) {   // reg-quad = 4 consecutive rows
                        const size_t row0 = brow + wm + mi * 32 + rg * 8 + 4 * half;
                        const size_t bb = row0 >> 10;
                        const int n0 = (int)(row0 & 1023);
                        ushort4_t o;
                        #pragma unroll
                        for (int q = 0; q < 4; q++) o[q] = f2bf(acc[mi][ni][rg * 4 + q]);
                        *(ushort4_t*)&vt[(((size_t)bb * HEADS + h) * HDIM + d) * SEQ + n0] = o;
                    }
                }
        }
    }
}

// ---------------------------------------------------------------------------
// MFMA flash attention, S^T formulation with 32x32x16 MFMA. ABM=128, 4 waves;
// wave w owns queries w*32 + (lane&31). Per 64-key tile (dbuf LDS, one
// barrier, register prefetch after the barrier):
//   S^T = K Q^T via 8 mfma_32x32x16 (2 key-row-tiles x 4 k-steps).
//   C-layout: col = query (lane&31) -> each lane owns ONE query; rows = keys
//   (r&3)+8(r>>2)+4*half (+t*32): lanes l and l+32 hold complementary key
//   halves -> lsum reduction is a single shfl_xor(32).
//   p = exp2(s) (Q pre-scaled; no max tracking); reg-quad = 4 consecutive
//   keys -> packed 8B P-write into Qs (LDH=72 rows, same-wave round-trip).
//   PV: A = P[query][key] (4 frags), B = V^T[dim][key] (8 frags) -> 8 mfma.
// 16 MFMAs/wave/tile at 8.07cyc (vs 32 x 4.85 for 16x16) = -17% matrix time;
// identical ds_read/exp/pack counts. Grid = (b*HEADS+h, qt): XCD-local K/V.
// ---------------------------------------------------------------------------
__global__ __launch_bounds__(256) void attn_mfma(const unsigned short* __restrict__ qk,
                                                 const unsigned short* __restrict__ vt,
                                                 unsigned short* __restrict__ aout) {
    const int bh = blockIdx.x;           // b*HEADS + h
    const int qt = blockIdx.y;           // 0..7
    const int h  = bh & 15;
    const int b  = bh >> 4;
    const int tid  = threadIdx.x;
    const int lane = tid & 63;
    const int wave = tid >> 6;
    const int c32  = lane & 31;   // query index within wave's 32
    const int half = lane >> 5;   // k-half / key-row-half selector

    __shared__ __align__(16) unsigned short Qs[ABM * LDH];      // Q then P
    __shared__ __align__(16) unsigned short Ks[2][64 * 64];     // swizzled
    __shared__ __align__(16) unsigned short Vs[2][64 * 64];     // V^T, swizzled
    __shared__ float scr[4][32];

    const int sr = tid >> 2;   // K/V staging row 0..63
    const int sq = tid & 3;    // two 16B chunks: 2sq, 2sq+1 (pre-swizzle)
    const int sx = sr & 7;     // staging row xor
    const unsigned short* ksrc0 =
        qk + ((size_t)(b * SEQ + sr)) * 2048 + DIM + h * HDIM + sq * 16;
    const unsigned short* vsrc0 =
        vt + (((size_t)(b * HEADS + h)) * HDIM + sr) * SEQ + sq * 16;
    // swizzled LDS staging offsets (bf16 units): row*64 + (chunk^xr)*8
    const int kvo0 = sr * 64 + (((sq * 2)     ^ sx) * 8);
    const int kvo1 = sr * 64 + (((sq * 2 + 1) ^ sx) * 8);

    // prefetch K/V tile 0 into registers
    ushort8_t ck0 = *(const ushort8_t*)ksrc0;
    ushort8_t ck1 = *(const ushort8_t*)(ksrc0 + 8);
    ushort8_t cv0 = *(const ushort8_t*)vsrc0;
    ushort8_t cv1 = *(const ushort8_t*)(vsrc0 + 8);

    // stage Q tile: 128 rows x 64 cols; thread -> row tid>>1, 32-col half
    {
        const int r  = tid >> 1;
        const int c0 = (tid & 1) * 32;
        const unsigned short* src =
            qk + ((size_t)(b * SEQ + qt * ABM + r)) * 2048 + h * HDIM + c0;
        unsigned short* dst = &Qs[r * LDH + c0];
        *(ushort8_t*)(dst)      = *(const ushort8_t*)(src);
        *(ushort8_t*)(dst + 8)  = *(const ushort8_t*)(src + 8);
        *(ushort8_t*)(dst + 16) = *(const ushort8_t*)(src + 16);
        *(ushort8_t*)(dst + 24) = *(const ushort8_t*)(src + 24);
    }
    __syncthreads();

    // Q B-fragments (4 k-steps of 16 dims), register-resident for the kernel
    short8_t bq[4];
    #pragma unroll
    for (int s = 0; s < 4; s++)
        bq[s] = *(const short8_t*)&Qs[(wave * 32 + c32) * LDH + s * 16 + half * 8];

    floatx16 O[2];   // O[dt]: rows = quad queries, col dim = dt*32 + c32
    #pragma unroll
    for (int dt = 0; dt < 2; dt++)
        #pragma unroll
        for (int r = 0; r < 16; r++) O[dt][r] = 0.f;
    float lsum = 0.f;

    const int fxr = c32 & 7;   // frag-read row xor (rows step by 32)

    for (int kt = 0; kt < SEQ / 64; kt++) {
        const int cur = kt & 1;
        // write prefetched K/V into buf[cur] (vmcnt wait lands here, a full
        // MFMA phase after the loads were issued)
        *(ushort8_t*)&Ks[cur][kvo0] = ck0;
        *(ushort8_t*)&Ks[cur][kvo1] = ck1;
        *(ushort8_t*)&Vs[cur][kvo0] = cv0;
        *(ushort8_t*)&Vs[cur][kvo1] = cv1;
        __syncthreads();   // ONE barrier per tile
        // issue next tile's global loads AFTER the barrier
        if (kt + 1 < SEQ / 64) {
            const unsigned short* ks = ksrc0 + (size_t)(kt + 1) * 64 * 2048;
            const unsigned short* vs = vsrc0 + (kt + 1) * 64;
            ck0 = *(const ushort8_t*)ks;
            ck1 = *(const ushort8_t*)(ks + 8);
            cv0 = *(const ushort8_t*)vs;
            cv1 = *(const ushort8_t*)(vs + 8);
        }

        // S^T = K Q^T : 2 key-row-tiles x 4 k-steps of 32x32x16
        floatx16 S[2];
        #pragma unroll
        for (int t = 0; t < 2; t++)
            #pragma unroll
            for (int r = 0; r < 16; r++) S[t][r] = 0.f;
        #pragma unroll
        for (int t = 0; t < 2; t++)
            #pragma unroll
            for (int s = 0; s < 4; s++) {
                const int slot = ((s * 2 + half) ^ fxr) * 8;
                short8_t ak = *(const short8_t*)&Ks[cur][(t * 32 + c32) * 64 + slot];
                S[t] = __builtin_amdgcn_mfma_f32_32x32x16_bf16(ak, bq[s], S[t], 0, 0, 0);
            }

        // p = exp2(s); accumulate l in-lane; quad = 4 consecutive keys -> 8B
        #pragma unroll
        for (int t = 0; t < 2; t++)
            #pragma unroll
            for (int rg = 0; rg < 4; rg++) {
                const float p0 = fast_exp2(S[t][rg * 4 + 0]);
                const float p1 = fast_exp2(S[t][rg * 4 + 1]);
                const float p2 = fast_exp2(S[t][rg * 4 + 2]);
                const float p3 = fast_exp2(S[t][rg * 4 + 3]);
                lsum += (p0 + p1) + (p2 + p3);
                const unsigned r01 = __builtin_amdgcn_perm(rnd_bf(p1), rnd_bf(p0), 0x07060302);
                const unsigned r23 = __builtin_amdgcn_perm(rnd_bf(p3), rnd_bf(p2), 0x07060302);
                *(uint2*)&Qs[(wave * 32 + c32) * LDH + t * 32 + rg * 8 + 4 * half] =
                    make_uint2(r01, r23);
            }

        // PV: O[query][dim] += P[query][key] V^T[dim][key]
        // A = P frags (same-wave LDS round-trip, in-order DS), B = V^T frags
        short8_t ap[4];
        #pragma unroll
        for (int s = 0; s < 4; s++)
            ap[s] = *(const short8_t*)&Qs[(wave * 32 + c32) * LDH + s * 16 + half * 8];
        #pragma unroll
        for (int dt = 0; dt < 2; dt++)
            #pragma unroll
            for (int s = 0; s < 4; s++) {
                const int slot = ((s * 2 + half) ^ fxr) * 8;
                short8_t bv = *(const short8_t*)&Vs[cur][(dt * 32 + c32) * 64 + slot];
                O[dt] = __builtin_amdgcn_mfma_f32_32x32x16_bf16(ap[s], bv, O[dt], 0, 0, 0);
            }
    }

    // epilogue: lanes l and l+32 hold complementary key-halves of query c32
    lsum += __shfl_xor(lsum, 32);
    if (half == 0) scr[wave][c32] = 1.0f / lsum;
    __builtin_amdgcn_s_waitcnt(0);   // lgkm drain for same-wave LDS ordering

    // O rows = quad queries (rg*8 + 4*half + 0..3); col dim = dt*32 + c32
    #pragma unroll
    for (int rg = 0; rg < 4; rg++) {
        const float4 inv4 = *(const float4*)&scr[wave][rg * 8 + 4 * half];
        #pragma unroll
        for (int q = 0; q < 4; q++) {
            const float invl = ((const float*)&inv4)[q];
            const size_t row = (size_t)b * SEQ + qt * ABM + wave * 32 + rg * 8 + 4 * half + q;
            #pragma unroll
            for (int dt = 0; dt < 2; dt++)
                aout[row * DIM + h * HDIM + dt * 32 + c32] = f2bf(O[dt][rg * 4 + q] * invl);
        }
    }
}

// ---------------------------------------------------------------------------
extern "C" void kernel_launch(void* const* d_in, const int* in_sizes, int n_in,
                              void* d_out, int out_size, void* d_ws, size_t ws_size,
                              hipStream_t stream) {
    const float* x      = (const float*)d_in[0];   // [8,1024,1024]
    const float* W_qkv  = (const float*)d_in[1];   // [3072,1024]
    const float* W_proj = (const float*)d_in[2];   // [1024,1024]
    const float* b_proj = (const float*)d_in[3];   // [1024]
    float* out = (float*)d_out;                    // [8,1024,1024] fp32

    const int M = BATCH * SEQ;                     // 8192

    // workspace (bf16 elements), ~92.3 MB total
    unsigned short* ws       = (unsigned short*)d_ws;
    unsigned short* x_bf     = ws;                                   // 8192*1024
    unsigned short* wqkv_bf  = x_bf + (size_t)M * DIM;               // 3072*1024
    unsigned short* wproj_bf = wqkv_bf + (size_t)3 * DIM * DIM;      // 1024*1024
    unsigned short* qk_bf    = wproj_bf + (size_t)DIM * DIM;         // 8192*2048
    unsigned short* vt_bf    = qk_bf + (size_t)M * 2048;             // 16*64*8*1024
    unsigned short* aout_bf  = vt_bf + (size_t)BATCH * HEADS * HDIM * SEQ;  // 8192*1024

    // 0) fused casts (x, W_qkv, W_proj)
    {
        const int n8 = (M * DIM + 3 * DIM * DIM + DIM * DIM) / 8;
        cvt_bf16_all<<<(n8 + 255) / 256, 256, 0, stream>>>(
            x, W_qkv, W_proj, x_bf, wqkv_bf, wproj_bf);
    }

    // 1) QKV projection: Q (pre-scaled) + K natural bf16, V -> vt[b][h][d][n]
    gemm_nt_mfma<2><<<dim3(M / 128, 3 * DIM / 128), 256, 0, stream>>>(
        x_bf, wqkv_bf, nullptr, qk_bf, vt_bf, M, 3 * DIM, DIM);

    // 2) MFMA flash attention; grid x = (b,h) so q-tiles share an XCD
    attn_mfma<<<dim3(BATCH * HEADS, SEQ / ABM), 256, 0, stream>>>(qk_bf, vt_bf, aout_bf);

    // 3) output projection (fp32 out + bias)
    gemm_nt_mfma<0><<<dim3(M / 128, DIM / 128), 256, 0, stream>>>(
        aout_bf, wproj_bf, b_proj, out, nullptr, M, DIM, DIM);
}